// Round 1
// baseline (4309.301 us; speedup 1.0000x reference)
//
#include <hip/hip_runtime.h>
#include <math.h>

#define BB 4
#define CC 64
#define NN 4096
#define OO 64
#define KNN 32
#define PADW 68

// ws layout (float offsets) — max footprint 23.66 MB (R0-proven)
#define XT_OFF    0u          // (B,N,C) fp32          1048576
#define SQ_OFF    1048576u    // (B,N) fp32             16384
#define P_OFF     1064960u    // (B,N,O)               1048576
#define BASE_OFF  2113536u    // (B,N,O)               1048576
#define HMAX_OFF  3162112u    // (B,N,O)               1048576
#define HMIN_OFF  4210688u    // (B,N,O)               1048576
#define STATS_OFF 5259264u    // 1024 x 128            131072
#define SCSH_OFF  5390336u    // 128
#define IDX_OFF   5390464u    // (B,N,K) int32         524288
// gap/i33 overlay the stats region (disjoint lifetimes: k2/k2f before k3)
#define GAP_OFF   5259264u    // (B*N) uint            16384
#define I33_OFF   5275648u    // (B*N) int              16384

__device__ __forceinline__ float keyToFloat(unsigned int u) {
  unsigned int b = (u & 0x80000000u) ? (u & 0x7fffffffu) : ~u;
  return __uint_as_float(b);
}

// ---------------- K1: transpose points (B,C,N)->(B,N,C) + fp32(sq64) ------
__global__ __launch_bounds__(256) void k1_transpose_sq(
    const float* __restrict__ pts, float* __restrict__ xT, float* __restrict__ sqf) {
  __shared__ float tile[64 * 65];
  __shared__ double sqp[256];
  const int t = threadIdx.x, blk = blockIdx.x;
  const int b = blk >> 6, n0 = (blk & 63) << 6;
  const float* pb = pts + (size_t)b * CC * NN;
  const int j = t & 63, cg = t >> 6;
  double acc = 0.0;
#pragma unroll
  for (int i = 0; i < 16; ++i) {
    int c = cg * 16 + i;
    float v = pb[(size_t)c * NN + n0 + j];
    tile[c * 65 + j] = v;
    acc += (double)v * (double)v;
  }
  sqp[t] = acc;
  __syncthreads();
  const int c2 = t & 63, jg = t >> 6;
#pragma unroll
  for (int i = 0; i < 16; ++i) {
    int jj = jg * 16 + i;
    xT[((size_t)b * NN + n0 + jj) * CC + c2] = tile[c2 * 65 + jj];
  }
  if (t < 64)
    sqf[b * NN + n0 + t] = (float)(sqp[t] + sqp[64 + t] + sqp[128 + t] + sqp[192 + t]);
}

// ---------------- K2b: P = x.w2^T, base = x.(w1-w2)^T ---------------------
__global__ __launch_bounds__(256) void k2b_small_gemm(
    const float* __restrict__ xT, const float* __restrict__ W,
    float* __restrict__ P, float* __restrict__ base) {
  __shared__ float w2T[64 * 65];
  __shared__ float wdT[64 * 65];
  __shared__ float xbuf[4 * 64];
  const int t = threadIdx.x, blk = blockIdx.x;
  const int b = blk >> 6, n0 = (blk & 63) << 6;
#pragma unroll
  for (int i = 0; i < 16; ++i) {
    int e = i * 256 + t, o = e >> 6, c = e & 63;
    w2T[c * 65 + o] = W[o * 128 + 64 + c];
  }
  __syncthreads();
#pragma unroll
  for (int i = 0; i < 16; ++i) {
    int e = i * 256 + t, o = e >> 6, c = e & 63;
    wdT[c * 65 + o] = W[o * 128 + c] - w2T[c * 65 + o];
  }
  __syncthreads();
  const int w = t >> 6, lane = t & 63;
  for (int it = 0; it < 16; ++it) {
    int n = n0 + it * 4 + w;
    xbuf[t] = xT[((size_t)b * NN + n) * CC + lane];
    __syncthreads();
    float accP = 0.f, accB = 0.f;
#pragma unroll
    for (int c = 0; c < 64; ++c) {
      float xc = xbuf[w * 64 + c];
      accP = fmaf(xc, w2T[c * 65 + lane], accP);
      accB = fmaf(xc, wdT[c * 65 + lane], accB);
    }
    size_t off = ((size_t)b * NN + n) * OO + lane;
    P[off] = accP;
    base[off] = accB;
    __syncthreads();
  }
}

// ---------------- K2: fp64 Gram + register-key binary-search select -------
// 2 rows/block, 256 threads. NEW STRUCTURE (this round):
//  - each thread holds BOTH row vectors in registers and owns one col of a
//    256-col tile -> each staged col vector is ds_read ONCE for two dots
//    (halves gram-phase LDS reads)
//  - per-thread keys (16 tiles x 2 rows) live in 32 VGPRs, statically
//    indexed via full unroll -> binary search / extraction are pure-VALU,
//    kbuf (36.9KB LDS) and its 32x re-read are gone
// All fp math expression-identical to the verified R-series kernel
// (same fma chain, same 2*g - srf - sq[col] order, same key transform).
__global__ __launch_bounds__(256, 2) void k2_gram_select(
    const float* __restrict__ xT, const float* __restrict__ sqf,
    int* __restrict__ idxout, unsigned int* __restrict__ gapb,
    int* __restrict__ i33out) {
  __shared__ __align__(16) float xmT[256 * PADW];  // 69632 B
  __shared__ int part[2][4];
  __shared__ int sh_list[2][32];
  __shared__ int sh_eq[2][96];
  __shared__ unsigned int sh_kmin[2];
  __shared__ int sh_ngt[2], sh_i33[2], sh_mx[2], sh_cnt[2], sh_ecnt[2];

  const int t = threadIdx.x, blk = blockIdx.x;
  const int p0 = blk * 2;
  const int b = p0 >> 12;
  const int wid = t >> 6;  // wave 0..3
  const float* xb = xT + (size_t)b * NN * CC;

  // both rows of the pair in registers (constant-indexed -> promoted)
  float4 xrA[16], xrB[16];
  {
    const float4* ra = (const float4*)(xT + (size_t)p0 * CC);
    const float4* rb = (const float4*)(xT + (size_t)(p0 + 1) * CC);
#pragma unroll
    for (int cq = 0; cq < 16; ++cq) {
      xrA[cq] = ra[cq];
      xrB[cq] = rb[cq];
    }
  }
  const float srfA = sqf[p0];
  const float srfB = sqf[p0 + 1];

  unsigned int k0[16], k1[16];  // keys: [tile] for row0 / row1, gi = tile*256 + t

#pragma unroll
  for (int tile = 0; tile < 16; ++tile) {
    const int m0 = tile << 8;
    __syncthreads();
#pragma unroll
    for (int q = 0; q < 16; ++q) {
      int e = q * 256 + t;
      int c2 = e >> 4, cq = e & 15;
      float4 v = ((const float4*)&xb[(size_t)(m0 + c2) * CC])[cq];
      *(float4*)&xmT[c2 * PADW + 4 * cq] = v;
    }
    float sqc = sqf[b * NN + m0 + t];
    __syncthreads();

    double accA = 0.0, accB = 0.0;
#pragma unroll
    for (int cq = 0; cq < 16; ++cq) {
      float4 mv = *(const float4*)&xmT[t * PADW + 4 * cq];
      accA += (double)xrA[cq].x * (double)mv.x + (double)xrA[cq].y * (double)mv.y +
              (double)xrA[cq].z * (double)mv.z + (double)xrA[cq].w * (double)mv.w;
      accB += (double)xrB[cq].x * (double)mv.x + (double)xrB[cq].y * (double)mv.y +
              (double)xrB[cq].z * (double)mv.z + (double)xrB[cq].w * (double)mv.w;
    }
    {
      float g = (float)accA;          // exact dot rounded once to fp32
      float d = 2.0f * g - srfA;      // same expression as verified kernel
      d = d - sqc;
      unsigned int bb2 = __float_as_uint(d);
      k0[tile] = (bb2 & 0x80000000u) ? ~bb2 : (bb2 | 0x80000000u);
    }
    {
      float g = (float)accB;
      float d = 2.0f * g - srfB;
      d = d - sqc;
      unsigned int bb2 = __float_as_uint(d);
      k1[tile] = (bb2 & 0x80000000u) ? ~bb2 : (bb2 | 0x80000000u);
    }
  }
  __syncthreads();

  // ---- binary search: K33 = 33rd-largest key, both rows at once ----
  // packed count: low 16 bits = row0, high 16 bits = row1 (max 4096 each)
  unsigned int PvA = 0, PvB = 0;
  int RA = 33, RB = 33;
  for (int bit = 31; bit >= 0; --bit) {
    unsigned int tgtA = (PvA >> bit) | 1u;
    unsigned int tgtB = (PvB >> bit) | 1u;
    int local = 0;
#pragma unroll
    for (int i = 0; i < 16; ++i) {
      local += ((k0[i] >> bit) == tgtA) ? 1 : 0;
      local += ((k1[i] >> bit) == tgtB) ? 0x10000 : 0;
    }
#pragma unroll
    for (int off = 32; off > 0; off >>= 1) local += __shfl_down(local, off, 64);
    if ((t & 63) == 0) part[bit & 1][wid] = local;
    __syncthreads();
    int S = part[bit & 1][0] + part[bit & 1][1] + part[bit & 1][2] + part[bit & 1][3];
    int c1A = S & 0xffff, c1B = S >> 16;
    if (c1A >= RA) PvA |= (1u << bit); else RA -= c1A;
    if (c1B >= RB) PvB |= (1u << bit); else RB -= c1B;
  }
  const unsigned int K33A = PvA, K33B = PvB;

  if (t < 2) {
    sh_ngt[t] = 0; sh_kmin[t] = 0xffffffffu; sh_i33[t] = 0x7fffffff;
    sh_mx[t] = -1; sh_cnt[t] = 0; sh_ecnt[t] = 0;
  }
  __syncthreads();

  int ngtA = 0, ngtB = 0;
  unsigned int kminA = 0xffffffffu, kminB = 0xffffffffu;
#pragma unroll
  for (int i = 0; i < 16; ++i) {
    int gi = (i << 8) + t;
    unsigned int ka = k0[i], kb = k1[i];
    if (ka > K33A) { ngtA++; kminA = ka < kminA ? ka : kminA; }
    if (ka == K33A) atomicMin(&sh_i33[0], gi);
    if (kb > K33B) { ngtB++; kminB = kb < kminB ? kb : kminB; }
    if (kb == K33B) atomicMin(&sh_i33[1], gi);
  }
  if (ngtA) { atomicAdd(&sh_ngt[0], ngtA); atomicMin(&sh_kmin[0], kminA); }
  if (ngtB) { atomicAdd(&sh_ngt[1], ngtB); atomicMin(&sh_kmin[1], kminB); }
  __syncthreads();

  const int ngt0 = sh_ngt[0], ngt1 = sh_ngt[1];
  const unsigned int K32A = (ngt0 == 32) ? sh_kmin[0] : K33A;
  const unsigned int K32B = (ngt1 == 32) ? sh_kmin[1] : K33B;
#pragma unroll
  for (int i = 0; i < 16; ++i) {
    int gi = (i << 8) + t;
    unsigned int ka = k0[i], kb = k1[i];
    if (ka > K33A) { int pos = atomicAdd(&sh_cnt[0], 1); sh_list[0][pos] = gi; }
    if (ngt0 == 32 && ka == K32A) atomicMax(&sh_mx[0], gi);
    if (ngt0 < 32 && ka == K33A) { int pos = atomicAdd(&sh_ecnt[0], 1); if (pos < 96) sh_eq[0][pos] = gi; }
    if (kb > K33B) { int pos = atomicAdd(&sh_cnt[1], 1); sh_list[1][pos] = gi; }
    if (ngt1 == 32 && kb == K32B) atomicMax(&sh_mx[1], gi);
    if (ngt1 < 32 && kb == K33B) { int pos = atomicAdd(&sh_ecnt[1], 1); if (pos < 96) sh_eq[1][pos] = gi; }
  }
  __syncthreads();

  if (t < 2) {
    const int row = t;
    const int p = p0 + row;
    const int ngt = sh_ngt[row];
    const unsigned int K33 = row ? K33B : K33A;
    if (ngt == 32) {
      const unsigned int K32 = sh_kmin[row];
      int target = sh_mx[row], pos = 31;
      for (int q2 = 0; q2 < 32; ++q2) if (sh_list[row][q2] == target) pos = q2;
      int tmp = sh_list[row][31]; sh_list[row][31] = sh_list[row][pos]; sh_list[row][pos] = tmp;
      gapb[p] = __float_as_uint(__fsub_rn(keyToFloat(K32), keyToFloat(K33)));
      i33out[p] = sh_i33[row];
    } else {
      int ec = sh_ecnt[row]; if (ec > 96) ec = 96;
      for (int a = 1; a < ec; ++a) {
        int v = sh_eq[row][a]; int bp = a - 1;
        while (bp >= 0 && sh_eq[row][bp] > v) { sh_eq[row][bp + 1] = sh_eq[row][bp]; --bp; }
        sh_eq[row][bp + 1] = v;
      }
      int need = 32 - ngt;
      for (int a = 0; a < need; ++a) sh_list[row][ngt + a] = sh_eq[row][a];
      gapb[p] = 0x7f800000u;
      i33out[p] = (need < ec) ? sh_eq[row][need] : -1;
    }
  }
  __syncthreads();
  if (t < 64) {
    int rr = t >> 5, k = t & 31;
    idxout[(size_t)(p0 + rr) * KNN + k] = sh_list[rr][k];
  }
}

// ---------------- K2f: flip the globally smallest-positive-gap row --------
__global__ __launch_bounds__(256) void k2f_flip(
    const unsigned int* __restrict__ gapb, const int* __restrict__ i33,
    int* __restrict__ idxout) {
  __shared__ unsigned int sk[256];
  __shared__ int sv[256];
  const int t = threadIdx.x;
  unsigned int best = 0xffffffffu;
  int brow = -1;
  for (int i = t; i < BB * NN; i += 256) {
    unsigned int g = gapb[i];
    if (g < best) { best = g; brow = i; }
  }
  sk[t] = best; sv[t] = brow;
  __syncthreads();
  for (int s = 128; s > 0; s >>= 1) {
    if (t < s && sk[t + s] < sk[t]) { sk[t] = sk[t + s]; sv[t] = sv[t + s]; }
    __syncthreads();
  }
  if (t == 0 && sv[0] >= 0 && sk[0] > 0u && sk[0] < 0x7f800000u) {
    idxout[(size_t)sv[0] * KNN + 31] = i33[sv[0]];
  }
}

// ---------------- K3: gather h=base+P[idx], k-max/min + BN partials -------
__global__ __launch_bounds__(256) void k3_gather_stats(
    const float* __restrict__ Pm, const float* __restrict__ basem,
    const int* __restrict__ idxb, float* __restrict__ hmax,
    float* __restrict__ hmin, float* __restrict__ statsP) {
  const int t = threadIdx.x, blk = blockIdx.x;
  const int w = t >> 6, o = t & 63;
  float s1 = 0.f, s2 = 0.f;
#pragma unroll
  for (int q = 0; q < 4; ++q) {
    int p = blk * 16 + w * 4 + q;
    int b = p >> 12;
    const float* Pb = Pm + (size_t)b * NN * OO;
    float bse = basem[(size_t)p * OO + o];
    const int* ix = idxb + (size_t)p * KNN;
    float mx = -INFINITY, mn = INFINITY;
#pragma unroll 8
    for (int k = 0; k < KNN; ++k) {
      int i = ix[k];
      float h = bse + Pb[(size_t)i * OO + o];
      mx = fmaxf(mx, h);
      mn = fminf(mn, h);
      s1 += h;
      s2 = fmaf(h, h, s2);
    }
    hmax[(size_t)p * OO + o] = mx;
    hmin[(size_t)p * OO + o] = mn;
  }
  __shared__ float red[512];
  red[t] = s1; red[256 + t] = s2;
  __syncthreads();
  if (t < 64) {
    statsP[blk * 128 + t]      = red[t] + red[64 + t] + red[128 + t] + red[192 + t];
    statsP[blk * 128 + 64 + t] = red[256 + t] + red[320 + t] + red[384 + t] + red[448 + t];
  }
}

// ---------------- K4: finalize BN scale/shift (256-thread reduction) ------
__global__ __launch_bounds__(256) void k4_finalize(
    const float* __restrict__ statsP, const float* __restrict__ gamma,
    const float* __restrict__ beta, float* __restrict__ scsh) {
  __shared__ float red1[256], red2[256];
  const int t = threadIdx.x;
  const int o = t & 63, c = t >> 6;
  float s1 = 0.f, s2 = 0.f;
  for (int i = c; i < 1024; i += 4) {
    s1 += statsP[i * 128 + o];
    s2 += statsP[i * 128 + 64 + o];
  }
  red1[t] = s1; red2[t] = s2;
  __syncthreads();
  if (t < 64) {
    s1 = red1[t] + red1[64 + t] + red1[128 + t] + red1[192 + t];
    s2 = red2[t] + red2[64 + t] + red2[128 + t] + red2[192 + t];
    const float inv = 1.0f / 524288.0f;
    float mean = s1 * inv;
    float var = s2 * inv - mean * mean;
    float r = rsqrtf(var + 1e-5f);
    float sc = gamma[t] * r;
    scsh[t] = sc;
    scsh[64 + t] = beta[t] - mean * sc;
  }
}

// ---------------- K5: epilogue: affine+relu on k-max/min, (B,O,N) --------
__global__ __launch_bounds__(256) void k5_epilogue(
    const float* __restrict__ hmax, const float* __restrict__ hmin,
    const float* __restrict__ scsh, float* __restrict__ out) {
  const int id = blockIdx.x * 256 + threadIdx.x;
  const int n = id & 4095, o = (id >> 12) & 63, b = id >> 18;
  float sc = scsh[o], sh = scsh[64 + o];
  size_t hoff = (((size_t)b << 12) + n) * OO + o;
  float H = (sc >= 0.f) ? hmax[hoff] : hmin[hoff];
  float y = sc * H + sh;
  out[id] = y > 0.f ? y : 0.f;
}

extern "C" void kernel_launch(void* const* d_in, const int* in_sizes, int n_in,
                              void* d_out, int out_size, void* d_ws, size_t ws_size,
                              hipStream_t stream) {
  const float* pts   = (const float*)d_in[0];
  const float* W     = (const float*)d_in[1];
  const float* gamma = (const float*)d_in[2];
  const float* beta  = (const float*)d_in[3];
  float* outp = (float*)d_out;
  float* wsf = (float*)d_ws;

  float*        xT    = wsf + XT_OFF;
  float*        sqf   = wsf + SQ_OFF;
  float*        P     = wsf + P_OFF;
  float*        base  = wsf + BASE_OFF;
  float*        hmax  = wsf + HMAX_OFF;
  float*        hmin  = wsf + HMIN_OFF;
  float*        stats = wsf + STATS_OFF;
  float*        scsh  = wsf + SCSH_OFF;
  int*          idx   = (int*)(wsf + IDX_OFF);
  unsigned int* gapb  = (unsigned int*)(wsf + GAP_OFF);
  int*          i33   = (int*)(wsf + I33_OFF);

  k1_transpose_sq<<<256, 256, 0, stream>>>(pts, xT, sqf);
  k2b_small_gemm<<<256, 256, 0, stream>>>(xT, W, P, base);
  k2_gram_select<<<8192, 256, 0, stream>>>(xT, sqf, idx, gapb, i33);
  k2f_flip<<<1, 256, 0, stream>>>(gapb, i33, idx);
  k3_gather_stats<<<1024, 256, 0, stream>>>(P, base, idx, hmax, hmin, stats);
  k4_finalize<<<1, 256, 0, stream>>>(stats, gamma, beta, scsh);
  k5_epilogue<<<4096, 256, 0, stream>>>(hmax, hmin, scsh, outp);
}

// Round 2
// 1181.376 us; speedup vs baseline: 3.6477x; 3.6477x over previous
//
#include <hip/hip_runtime.h>
#include <math.h>

#define BB 4
#define CC 64
#define NN 4096
#define OO 64
#define KNN 32
#define PADW 68

// ws layout (float offsets) — max footprint 23.66 MB (R0-proven)
#define XT_OFF    0u          // (B,N,C) fp32          1048576
#define SQ_OFF    1048576u    // (B,N) fp32             16384
#define P_OFF     1064960u    // (B,N,O)               1048576
#define BASE_OFF  2113536u    // (B,N,O)               1048576
#define HMAX_OFF  3162112u    // (B,N,O)               1048576
#define HMIN_OFF  4210688u    // (B,N,O)               1048576
#define STATS_OFF 5259264u    // 1024 x 128            131072
#define SCSH_OFF  5390336u    // 128
#define IDX_OFF   5390464u    // (B,N,K) int32         524288
// gap/i33 overlay the stats region (disjoint lifetimes: k2/k2f before k3)
#define GAP_OFF   5259264u    // (B*N) uint            16384
#define I33_OFF   5275648u    // (B*N) int              16384

__device__ __forceinline__ float keyToFloat(unsigned int u) {
  unsigned int b = (u & 0x80000000u) ? (u & 0x7fffffffu) : ~u;
  return __uint_as_float(b);
}

// ---------------- K1: transpose points (B,C,N)->(B,N,C) + fp32(sq64) ------
__global__ __launch_bounds__(256) void k1_transpose_sq(
    const float* __restrict__ pts, float* __restrict__ xT, float* __restrict__ sqf) {
  __shared__ float tile[64 * 65];
  __shared__ double sqp[256];
  const int t = threadIdx.x, blk = blockIdx.x;
  const int b = blk >> 6, n0 = (blk & 63) << 6;
  const float* pb = pts + (size_t)b * CC * NN;
  const int j = t & 63, cg = t >> 6;
  double acc = 0.0;
#pragma unroll
  for (int i = 0; i < 16; ++i) {
    int c = cg * 16 + i;
    float v = pb[(size_t)c * NN + n0 + j];
    tile[c * 65 + j] = v;
    acc += (double)v * (double)v;
  }
  sqp[t] = acc;
  __syncthreads();
  const int c2 = t & 63, jg = t >> 6;
#pragma unroll
  for (int i = 0; i < 16; ++i) {
    int jj = jg * 16 + i;
    xT[((size_t)b * NN + n0 + jj) * CC + c2] = tile[c2 * 65 + jj];
  }
  if (t < 64)
    sqf[b * NN + n0 + t] = (float)(sqp[t] + sqp[64 + t] + sqp[128 + t] + sqp[192 + t]);
}

// ---------------- K2b: P = x.w2^T, base = x.(w1-w2)^T ---------------------
__global__ __launch_bounds__(256) void k2b_small_gemm(
    const float* __restrict__ xT, const float* __restrict__ W,
    float* __restrict__ P, float* __restrict__ base) {
  __shared__ float w2T[64 * 65];
  __shared__ float wdT[64 * 65];
  __shared__ float xbuf[4 * 64];
  const int t = threadIdx.x, blk = blockIdx.x;
  const int b = blk >> 6, n0 = (blk & 63) << 6;
#pragma unroll
  for (int i = 0; i < 16; ++i) {
    int e = i * 256 + t, o = e >> 6, c = e & 63;
    w2T[c * 65 + o] = W[o * 128 + 64 + c];
  }
  __syncthreads();
#pragma unroll
  for (int i = 0; i < 16; ++i) {
    int e = i * 256 + t, o = e >> 6, c = e & 63;
    wdT[c * 65 + o] = W[o * 128 + c] - w2T[c * 65 + o];
  }
  __syncthreads();
  const int w = t >> 6, lane = t & 63;
  for (int it = 0; it < 16; ++it) {
    int n = n0 + it * 4 + w;
    xbuf[t] = xT[((size_t)b * NN + n) * CC + lane];
    __syncthreads();
    float accP = 0.f, accB = 0.f;
#pragma unroll
    for (int c = 0; c < 64; ++c) {
      float xc = xbuf[w * 64 + c];
      accP = fmaf(xc, w2T[c * 65 + lane], accP);
      accB = fmaf(xc, wdT[c * 65 + lane], accB);
    }
    size_t off = ((size_t)b * NN + n) * OO + lane;
    P[off] = accP;
    base[off] = accB;
    __syncthreads();
  }
}

// ---------------- K2: fp64 Gram + REGISTER-key binary-search select -------
// Layout = verified baseline (2 rows/block, row=t>>7, col=t&127, 32 tiles
// of 128 cols; one row vector per thread = 64 VGPR). CHANGE vs baseline:
// the 32 per-thread keys live in VGPRs (statically indexed), not in a
// 36.9KB LDS kbuf — removes ~300 b128 LDS re-reads/thread in the binary
// search + extraction and frees the LDS (71.7KB -> ~35.5KB).
// All fp math expression-identical to the verified kernel.
__global__ __launch_bounds__(256, 2) void k2_gram_select(
    const float* __restrict__ xT, const float* __restrict__ sqf,
    int* __restrict__ idxout, unsigned int* __restrict__ gapb,
    int* __restrict__ i33out) {
  __shared__ __align__(16) float xmT[128 * PADW];  // 34816 B
  __shared__ float sqm[128];
  __shared__ int rowcnt[2][4];
  __shared__ int sh_list[2][32];
  __shared__ int sh_eq[2][96];
  __shared__ unsigned int sh_kmin[2];
  __shared__ int sh_ngt[2], sh_i33[2], sh_mx[2], sh_cnt[2], sh_ecnt[2];

  const int t = threadIdx.x, blk = blockIdx.x;
  const int p0 = blk * 2;
  const int b = p0 >> 12;
  const int row = t >> 7;     // 0/1
  const int col = t & 127;
  const int wid = t >> 6;     // wave 0..3
  const float* xb = xT + (size_t)b * NN * CC;

  // this thread's row vector in registers (constant-indexed -> promoted)
  float4 xr4[16];
  {
    const float4* xrp = (const float4*)(xT + (size_t)(p0 + row) * CC);
#pragma unroll
    for (int cq = 0; cq < 16; ++cq) xr4[cq] = xrp[cq];
  }
  const float srf = sqf[p0 + row];

  unsigned int keys[32];  // key for col at gi = tile*128 + col

  for (int tile = 0; tile < 32; ++tile) {
    const int m0 = tile << 7;
    __syncthreads();
#pragma unroll
    for (int q = 0; q < 8; ++q) {
      int e = q * 256 + t;
      int c2 = e >> 4, cq = e & 15;
      float4 v = ((const float4*)&xb[(size_t)(m0 + c2) * CC])[cq];
      *(float4*)&xmT[c2 * PADW + 4 * cq] = v;
    }
    if (t < 128) sqm[t] = sqf[b * NN + m0 + t];
    __syncthreads();

    double acc = 0.0;
#pragma unroll
    for (int cq = 0; cq < 16; ++cq) {
      float4 mv = *(const float4*)&xmT[col * PADW + 4 * cq];
      acc += (double)xr4[cq].x * (double)mv.x + (double)xr4[cq].y * (double)mv.y +
             (double)xr4[cq].z * (double)mv.z + (double)xr4[cq].w * (double)mv.w;
    }
    float g = (float)acc;           // exact dot rounded once to fp32
    float d = 2.0f * g - srf;       // same expression as verified kernel
    d = d - sqm[col];
    unsigned int bb2 = __float_as_uint(d);
    keys[tile] = (bb2 & 0x80000000u) ? ~bb2 : (bb2 | 0x80000000u);
  }
  __syncthreads();

  // ---- binary search: K33 = 33rd-largest key of this row (keys in regs) --
  unsigned int Pv = 0;
  int R = 33;
  for (int bit = 31; bit >= 0; --bit) {
    unsigned int tgt = (Pv >> bit) | 1u;
    int local = 0;
#pragma unroll
    for (int i = 0; i < 32; ++i) local += ((keys[i] >> bit) == tgt) ? 1 : 0;
#pragma unroll
    for (int off = 32; off > 0; off >>= 1) local += __shfl_down(local, off, 64);
    if ((t & 63) == 0) rowcnt[bit & 1][wid] = local;
    __syncthreads();
    int c1 = rowcnt[bit & 1][row * 2] + rowcnt[bit & 1][row * 2 + 1];
    if (c1 >= R) Pv |= (1u << bit); else R -= c1;
  }
  const unsigned int K33 = Pv;

  if ((t & 127) == 0) {
    sh_ngt[row] = 0; sh_kmin[row] = 0xffffffffu; sh_i33[row] = 0x7fffffff;
    sh_mx[row] = -1; sh_cnt[row] = 0; sh_ecnt[row] = 0;
  }
  __syncthreads();

  int ngt_loc = 0;
  unsigned int kmin_loc = 0xffffffffu;
#pragma unroll
  for (int i = 0; i < 32; ++i) {
    unsigned int kq = keys[i];
    int gi = (i << 7) + col;
    if (kq > K33) { ngt_loc++; kmin_loc = kq < kmin_loc ? kq : kmin_loc; }
    if (kq == K33) atomicMin(&sh_i33[row], gi);
  }
  if (ngt_loc) { atomicAdd(&sh_ngt[row], ngt_loc); atomicMin(&sh_kmin[row], kmin_loc); }
  __syncthreads();

  const int ngt = sh_ngt[row];
  const unsigned int K32 = (ngt == 32) ? sh_kmin[row] : K33;
#pragma unroll
  for (int i = 0; i < 32; ++i) {
    unsigned int kq = keys[i];
    int gi = (i << 7) + col;
    if (kq > K33) { int pos = atomicAdd(&sh_cnt[row], 1); sh_list[row][pos] = gi; }
    if (ngt == 32 && kq == K32) atomicMax(&sh_mx[row], gi);
    if (ngt < 32 && kq == K33) { int pos = atomicAdd(&sh_ecnt[row], 1); if (pos < 96) sh_eq[row][pos] = gi; }
  }
  __syncthreads();

  if ((t & 127) == 0) {
    const int p = p0 + row;
    if (ngt == 32) {
      int target = sh_mx[row], pos = 31;
      for (int q2 = 0; q2 < 32; ++q2) if (sh_list[row][q2] == target) pos = q2;
      int tmp = sh_list[row][31]; sh_list[row][31] = sh_list[row][pos]; sh_list[row][pos] = tmp;
      gapb[p] = __float_as_uint(__fsub_rn(keyToFloat(K32), keyToFloat(K33)));
      i33out[p] = sh_i33[row];
    } else {
      int ec = sh_ecnt[row]; if (ec > 96) ec = 96;
      for (int a = 1; a < ec; ++a) {
        int v = sh_eq[row][a]; int bp = a - 1;
        while (bp >= 0 && sh_eq[row][bp] > v) { sh_eq[row][bp + 1] = sh_eq[row][bp]; --bp; }
        sh_eq[row][bp + 1] = v;
      }
      int need = 32 - ngt;
      for (int a = 0; a < need; ++a) sh_list[row][ngt + a] = sh_eq[row][a];
      gapb[p] = 0x7f800000u;
      i33out[p] = (need < ec) ? sh_eq[row][need] : -1;
    }
  }
  __syncthreads();
  if (t < 64) {
    int rr = t >> 5, k = t & 31;
    idxout[(size_t)(p0 + rr) * KNN + k] = sh_list[rr][k];
  }
}

// ---------------- K2f: flip the globally smallest-positive-gap row --------
__global__ __launch_bounds__(256) void k2f_flip(
    const unsigned int* __restrict__ gapb, const int* __restrict__ i33,
    int* __restrict__ idxout) {
  __shared__ unsigned int sk[256];
  __shared__ int sv[256];
  const int t = threadIdx.x;
  unsigned int best = 0xffffffffu;
  int brow = -1;
  for (int i = t; i < BB * NN; i += 256) {
    unsigned int g = gapb[i];
    if (g < best) { best = g; brow = i; }
  }
  sk[t] = best; sv[t] = brow;
  __syncthreads();
  for (int s = 128; s > 0; s >>= 1) {
    if (t < s && sk[t + s] < sk[t]) { sk[t] = sk[t + s]; sv[t] = sv[t + s]; }
    __syncthreads();
  }
  if (t == 0 && sv[0] >= 0 && sk[0] > 0u && sk[0] < 0x7f800000u) {
    idxout[(size_t)sv[0] * KNN + 31] = i33[sv[0]];
  }
}

// ---------------- K3: gather h=base+P[idx], k-max/min + BN partials -------
__global__ __launch_bounds__(256) void k3_gather_stats(
    const float* __restrict__ Pm, const float* __restrict__ basem,
    const int* __restrict__ idxb, float* __restrict__ hmax,
    float* __restrict__ hmin, float* __restrict__ statsP) {
  const int t = threadIdx.x, blk = blockIdx.x;
  const int w = t >> 6, o = t & 63;
  float s1 = 0.f, s2 = 0.f;
#pragma unroll
  for (int q = 0; q < 4; ++q) {
    int p = blk * 16 + w * 4 + q;
    int b = p >> 12;
    const float* Pb = Pm + (size_t)b * NN * OO;
    float bse = basem[(size_t)p * OO + o];
    const int* ix = idxb + (size_t)p * KNN;
    float mx = -INFINITY, mn = INFINITY;
#pragma unroll 8
    for (int k = 0; k < KNN; ++k) {
      int i = ix[k];
      float h = bse + Pb[(size_t)i * OO + o];
      mx = fmaxf(mx, h);
      mn = fminf(mn, h);
      s1 += h;
      s2 = fmaf(h, h, s2);
    }
    hmax[(size_t)p * OO + o] = mx;
    hmin[(size_t)p * OO + o] = mn;
  }
  __shared__ float red[512];
  red[t] = s1; red[256 + t] = s2;
  __syncthreads();
  if (t < 64) {
    statsP[blk * 128 + t]      = red[t] + red[64 + t] + red[128 + t] + red[192 + t];
    statsP[blk * 128 + 64 + t] = red[256 + t] + red[320 + t] + red[384 + t] + red[448 + t];
  }
}

// ---------------- K4: finalize BN scale/shift (256-thread reduction) ------
__global__ __launch_bounds__(256) void k4_finalize(
    const float* __restrict__ statsP, const float* __restrict__ gamma,
    const float* __restrict__ beta, float* __restrict__ scsh) {
  __shared__ float red1[256], red2[256];
  const int t = threadIdx.x;
  const int o = t & 63, c = t >> 6;
  float s1 = 0.f, s2 = 0.f;
  for (int i = c; i < 1024; i += 4) {
    s1 += statsP[i * 128 + o];
    s2 += statsP[i * 128 + 64 + o];
  }
  red1[t] = s1; red2[t] = s2;
  __syncthreads();
  if (t < 64) {
    s1 = red1[t] + red1[64 + t] + red1[128 + t] + red1[192 + t];
    s2 = red2[t] + red2[64 + t] + red2[128 + t] + red2[192 + t];
    const float inv = 1.0f / 524288.0f;
    float mean = s1 * inv;
    float var = s2 * inv - mean * mean;
    float r = rsqrtf(var + 1e-5f);
    float sc = gamma[t] * r;
    scsh[t] = sc;
    scsh[64 + t] = beta[t] - mean * sc;
  }
}

// ---------------- K5: epilogue: affine+relu on k-max/min, (B,O,N) --------
__global__ __launch_bounds__(256) void k5_epilogue(
    const float* __restrict__ hmax, const float* __restrict__ hmin,
    const float* __restrict__ scsh, float* __restrict__ out) {
  const int id = blockIdx.x * 256 + threadIdx.x;
  const int n = id & 4095, o = (id >> 12) & 63, b = id >> 18;
  float sc = scsh[o], sh = scsh[64 + o];
  size_t hoff = (((size_t)b << 12) + n) * OO + o;
  float H = (sc >= 0.f) ? hmax[hoff] : hmin[hoff];
  float y = sc * H + sh;
  out[id] = y > 0.f ? y : 0.f;
}

extern "C" void kernel_launch(void* const* d_in, const int* in_sizes, int n_in,
                              void* d_out, int out_size, void* d_ws, size_t ws_size,
                              hipStream_t stream) {
  const float* pts   = (const float*)d_in[0];
  const float* W     = (const float*)d_in[1];
  const float* gamma = (const float*)d_in[2];
  const float* beta  = (const float*)d_in[3];
  float* outp = (float*)d_out;
  float* wsf = (float*)d_ws;

  float*        xT    = wsf + XT_OFF;
  float*        sqf   = wsf + SQ_OFF;
  float*        P     = wsf + P_OFF;
  float*        base  = wsf + BASE_OFF;
  float*        hmax  = wsf + HMAX_OFF;
  float*        hmin  = wsf + HMIN_OFF;
  float*        stats = wsf + STATS_OFF;
  float*        scsh  = wsf + SCSH_OFF;
  int*          idx   = (int*)(wsf + IDX_OFF);
  unsigned int* gapb  = (unsigned int*)(wsf + GAP_OFF);
  int*          i33   = (int*)(wsf + I33_OFF);

  k1_transpose_sq<<<256, 256, 0, stream>>>(pts, xT, sqf);
  k2b_small_gemm<<<256, 256, 0, stream>>>(xT, W, P, base);
  k2_gram_select<<<8192, 256, 0, stream>>>(xT, sqf, idx, gapb, i33);
  k2f_flip<<<1, 256, 0, stream>>>(gapb, i33, idx);
  k3_gather_stats<<<1024, 256, 0, stream>>>(P, base, idx, hmax, hmin, stats);
  k4_finalize<<<1, 256, 0, stream>>>(stats, gamma, beta, scsh);
  k5_epilogue<<<4096, 256, 0, stream>>>(hmax, hmin, scsh, outp);
}